// Round 1
// baseline (562.097 us; speedup 1.0000x reference)
//
#include <hip/hip_runtime.h>
#include <hip/hip_bf16.h>
#include <math.h>

#define B_ 32
#define H_ 1024
#define S_ 1024

typedef __bf16 bf16x4_t __attribute__((ext_vector_type(4)));
typedef __bf16 bf16x8_t __attribute__((ext_vector_type(8)));
typedef float f32x4_t __attribute__((ext_vector_type(4)));

// ---------------------------------------------------------------------------
// t1[b,h] = bias[h] + sum_k hidden[b,k] * W[h, k]   (W1 = first H cols of W)
// ---------------------------------------------------------------------------
__global__ __launch_bounds__(256) void term1_kernel(
    const float* __restrict__ hidden, const float* __restrict__ W,
    const float* __restrict__ bias, float* __restrict__ t1)
{
    int b = blockIdx.y;
    int h = blockIdx.x * 256 + threadIdx.x;
    const float4* hp = reinterpret_cast<const float4*>(hidden + b * H_);
    const float4* wp = reinterpret_cast<const float4*>(W + (size_t)h * (2 * H_));
    float acc = 0.f;
    #pragma unroll 4
    for (int k = 0; k < H_ / 4; ++k) {
        float4 hv = hp[k];
        float4 wv = wp[k];
        acc += hv.x * wv.x + hv.y * wv.y + hv.z * wv.z + hv.w * wv.w;
    }
    t1[b * H_ + h] = acc + bias[h];
}

// ---------------------------------------------------------------------------
// Fused per-batch GEMM + tanh + v-dot:
//   D[h,s] = sum_k W2[h,k] * enc[b,k,s]      (M=h, N=s, K=k; W2 = W[:,H:])
//   logits[b,s] += sum_h v[h] * tanh(D[h,s] + t1[b,h])
// 128x128 tile, BK=32, 4 waves each computing 4x4 MFMA 16x16x32 tiles.
// ---------------------------------------------------------------------------
#define TM 128
#define TN 128
#define TK 32
#define LDT 40  // LDS row stride in bf16 (32 + 8 pad, keeps 16B alignment)

__global__ __launch_bounds__(256) void energy_kernel(
    const float* __restrict__ enc,   // [B,S,H]
    const float* __restrict__ W,     // [H,2H]
    const float* __restrict__ t1,    // [B,H] (includes bias)
    const float* __restrict__ v,     // [H]
    float* __restrict__ logits)      // [B,S], pre-zeroed
{
    __shared__ __align__(16) __bf16 As[TM * LDT];  // As[m][k] = W2[h0+m][k0+k]
    __shared__ __align__(16) __bf16 Bs[TN * LDT];  // Bs[n][k] = enc[b][k0+k][s0+n]

    const int b    = blockIdx.z;
    const int h0   = blockIdx.x * TM;
    const int s0   = blockIdx.y * TN;
    const int tid  = threadIdx.x;
    const int lane = tid & 63;
    const int wid  = tid >> 6;
    const int wm   = (wid & 1) * 64;   // wave m offset in tile
    const int wn   = (wid >> 1) * 64;  // wave n offset in tile
    const int quad = lane >> 4;
    const int l16  = lane & 15;

    f32x4_t acc[4][4] = {};

    for (int k0 = 0; k0 < H_; k0 += TK) {
        // --- stage A tile (W2 rows, layout-preserving, bf16x4 vector writes)
        #pragma unroll
        for (int i = 0; i < 4; ++i) {
            int flat = tid + i * 256;  // 0..1023 over 128 rows x 8 float4
            int m    = flat >> 3;
            int kq   = flat & 7;
            const float4 wv = *reinterpret_cast<const float4*>(
                W + (size_t)(h0 + m) * (2 * H_) + H_ + k0 + kq * 4);
            bf16x4_t p = { (__bf16)wv.x, (__bf16)wv.y, (__bf16)wv.z, (__bf16)wv.w };
            *reinterpret_cast<bf16x4_t*>(&As[m * LDT + kq * 4]) = p;
        }
        // --- stage B tile (enc rows, transposed into Bs[n][k]; scalar writes)
        #pragma unroll
        for (int i = 0; i < 4; ++i) {
            int flat = tid + i * 256;  // 0..1023 over 32 k-rows x 32 float4
            int kl   = flat >> 5;
            int nc   = flat & 31;
            const float4 ev = *reinterpret_cast<const float4*>(
                enc + ((size_t)b * S_ + (k0 + kl)) * H_ + s0 + nc * 4);
            int n = nc * 4;
            Bs[(n + 0) * LDT + kl] = (__bf16)ev.x;
            Bs[(n + 1) * LDT + kl] = (__bf16)ev.y;
            Bs[(n + 2) * LDT + kl] = (__bf16)ev.z;
            Bs[(n + 3) * LDT + kl] = (__bf16)ev.w;
        }
        __syncthreads();

        bf16x8_t af[4], bfr[4];
        #pragma unroll
        for (int mi = 0; mi < 4; ++mi)
            af[mi] = *reinterpret_cast<const bf16x8_t*>(
                &As[(wm + mi * 16 + l16) * LDT + quad * 8]);
        #pragma unroll
        for (int ni = 0; ni < 4; ++ni)
            bfr[ni] = *reinterpret_cast<const bf16x8_t*>(
                &Bs[(wn + ni * 16 + l16) * LDT + quad * 8]);
        #pragma unroll
        for (int mi = 0; mi < 4; ++mi)
            #pragma unroll
            for (int ni = 0; ni < 4; ++ni)
                acc[mi][ni] = __builtin_amdgcn_mfma_f32_16x16x32_bf16(
                    af[mi], bfr[ni], acc[mi][ni], 0, 0, 0);
        __syncthreads();
    }

    // --- epilogue: logits[b,s] += sum over this tile's 128 h of v*tanh(.+t1)
    float tv[4][4], vv[4][4];
    #pragma unroll
    for (int mi = 0; mi < 4; ++mi)
        #pragma unroll
        for (int r = 0; r < 4; ++r) {
            int m = h0 + wm + mi * 16 + quad * 4 + r;  // D row = quad*4 + reg
            tv[mi][r] = t1[b * H_ + m];
            vv[mi][r] = v[m];
        }
    #pragma unroll
    for (int ni = 0; ni < 4; ++ni) {
        float p = 0.f;
        #pragma unroll
        for (int mi = 0; mi < 4; ++mi)
            #pragma unroll
            for (int r = 0; r < 4; ++r)
                p += vv[mi][r] * tanhf(acc[mi][ni][r] + tv[mi][r]);
        p += __shfl_xor(p, 16);
        p += __shfl_xor(p, 32);
        if (quad == 0)
            atomicAdd(&logits[(size_t)b * S_ + s0 + wn + ni * 16 + l16], p);
    }
}

// ---------------------------------------------------------------------------
// softmax over s (per batch row of 1024); logits are tiny (~1e-2) but do the
// max-subtraction anyway.
// ---------------------------------------------------------------------------
__global__ __launch_bounds__(256) void softmax_kernel(
    const float* __restrict__ logits, float* __restrict__ scores)
{
    int b = blockIdx.x, tid = threadIdx.x;
    float x[4];
    float mx = -3.4e38f;
    #pragma unroll
    for (int i = 0; i < 4; ++i) {
        x[i] = logits[b * S_ + tid + i * 256];
        mx = fmaxf(mx, x[i]);
    }
    #pragma unroll
    for (int off = 1; off < 64; off <<= 1) mx = fmaxf(mx, __shfl_xor(mx, off));
    __shared__ float sm[4], ss[4];
    if ((tid & 63) == 0) sm[tid >> 6] = mx;
    __syncthreads();
    mx = fmaxf(fmaxf(sm[0], sm[1]), fmaxf(sm[2], sm[3]));
    float s = 0.f;
    #pragma unroll
    for (int i = 0; i < 4; ++i) {
        x[i] = expf(x[i] - mx);
        s += x[i];
    }
    #pragma unroll
    for (int off = 1; off < 64; off <<= 1) s += __shfl_xor(s, off);
    if ((tid & 63) == 0) ss[tid >> 6] = s;
    __syncthreads();
    float inv = 1.f / (ss[0] + ss[1] + ss[2] + ss[3]);
    #pragma unroll
    for (int i = 0; i < 4; ++i)
        scores[b * S_ + tid + i * 256] = x[i] * inv;
}

// ---------------------------------------------------------------------------
// context[b,h] = sum_s scores[b,s] * enc[b,s,h]   (ctx pre-zeroed; s-split +
// atomicAdd for occupancy: 512 blocks)
// ---------------------------------------------------------------------------
__global__ __launch_bounds__(256) void context_kernel(
    const float* __restrict__ enc, const float* __restrict__ scores,
    float* __restrict__ ctx)
{
    int b     = blockIdx.z;
    int h     = blockIdx.x * 256 + threadIdx.x;
    int sbase = blockIdx.y * 256;
    float acc = 0.f;
    for (int s = 0; s < 256; ++s) {
        acc += scores[b * S_ + sbase + s] *
               enc[((size_t)b * S_ + sbase + s) * H_ + h];
    }
    atomicAdd(&ctx[b * H_ + h], acc);
}

// ---------------------------------------------------------------------------
extern "C" void kernel_launch(void* const* d_in, const int* in_sizes, int n_in,
                              void* d_out, int out_size, void* d_ws, size_t ws_size,
                              hipStream_t stream)
{
    (void)in_sizes; (void)n_in; (void)out_size; (void)ws_size;
    const float* hidden = (const float*)d_in[0];
    const float* enc    = (const float*)d_in[1];
    const float* W      = (const float*)d_in[2];
    const float* bias   = (const float*)d_in[3];
    const float* v      = (const float*)d_in[4];

    float* out    = (float*)d_out;
    float* ctx    = out;             // [B,H]
    float* scores = out + B_ * H_;   // [B,S] (flat [B,1,S])

    float* logits = (float*)d_ws;            // B*S floats
    float* t1     = (float*)d_ws + B_ * S_;  // B*H floats

    hipMemsetAsync(logits, 0, (size_t)B_ * S_ * sizeof(float), stream);
    hipMemsetAsync(ctx, 0, (size_t)B_ * H_ * sizeof(float), stream);

    term1_kernel<<<dim3(H_ / 256, B_), 256, 0, stream>>>(hidden, W, bias, t1);
    energy_kernel<<<dim3(H_ / TM, S_ / TN, B_), 256, 0, stream>>>(
        enc, W, t1, v, logits);
    softmax_kernel<<<B_, 256, 0, stream>>>(logits, scores);
    context_kernel<<<dim3(H_ / 256, S_ / 256, B_), 256, 0, stream>>>(
        enc, scores, ctx);
}

// Round 2
// 366.104 us; speedup vs baseline: 1.5353x; 1.5353x over previous
//
#include <hip/hip_runtime.h>
#include <hip/hip_bf16.h>
#include <math.h>

#define B_ 32
#define H_ 1024
#define S_ 1024

typedef __bf16 bf16x4_t __attribute__((ext_vector_type(4)));
typedef __bf16 bf16x8_t __attribute__((ext_vector_type(8)));
typedef float f32x4_t __attribute__((ext_vector_type(4)));

// async global->LDS, 16B per lane. LDS dest must be wave-uniform base + lane*16;
// our per-thread lptr = base + tid*16 satisfies this exactly (no padding).
__device__ __forceinline__ void gl_lds16(const void* g, void* l) {
    __builtin_amdgcn_global_load_lds(
        (const __attribute__((address_space(1))) uint32_t*)g,
        (__attribute__((address_space(3))) uint32_t*)l,
        16, 0, 0);
}

// ---------------------------------------------------------------------------
// t1[b,h] = bias[h] + sum_k hidden[b,k]*W[h,k].  Wave-per-h: coalesced W rows.
// ---------------------------------------------------------------------------
__global__ __launch_bounds__(256) void term1_kernel(
    const float* __restrict__ hidden, const float* __restrict__ W,
    const float* __restrict__ bias, float* __restrict__ t1)
{
    int b    = blockIdx.y;
    int h    = blockIdx.x * 4 + (threadIdx.x >> 6);
    int lane = threadIdx.x & 63;
    const float4* wp = reinterpret_cast<const float4*>(W + (size_t)h * (2 * H_));
    const float4* hp = reinterpret_cast<const float4*>(hidden + b * H_);
    float acc = 0.f;
    #pragma unroll
    for (int j = 0; j < 4; ++j) {
        float4 wv = wp[lane + j * 64];
        float4 hv = hp[lane + j * 64];
        acc += wv.x * hv.x + wv.y * hv.y + wv.z * hv.z + wv.w * hv.w;
    }
    #pragma unroll
    for (int off = 1; off < 64; off <<= 1) acc += __shfl_xor(acc, off);
    if (lane == 0) t1[b * H_ + h] = acc + bias[h];
}

// ---------------------------------------------------------------------------
// encT[b][s][j] = (bf16) enc[b][j][s].  64x64 tiles via LDS (pad 65 -> all
// LDS scalar ops are <=2-way bank aliased = free).
// ---------------------------------------------------------------------------
__global__ __launch_bounds__(256) void transpose_kernel(
    const float* __restrict__ enc, __bf16* __restrict__ encT)
{
    __shared__ float T[64 * 65];
    const int b   = blockIdx.z;
    const int k0  = blockIdx.x * 64;  // enc row tile (reduction axis j)
    const int s0  = blockIdx.y * 64;  // enc col tile
    const int tid = threadIdx.x;
    #pragma unroll
    for (int it = 0; it < 4; ++it) {
        int flat = tid + it * 256;   // 64 rows x 16 float4
        int r  = flat >> 4;
        int c4 = flat & 15;
        float4 vv = *reinterpret_cast<const float4*>(
            enc + ((size_t)b * S_ + k0 + r) * H_ + s0 + c4 * 4);
        T[r * 65 + c4 * 4 + 0] = vv.x;
        T[r * 65 + c4 * 4 + 1] = vv.y;
        T[r * 65 + c4 * 4 + 2] = vv.z;
        T[r * 65 + c4 * 4 + 3] = vv.w;
    }
    __syncthreads();
    #pragma unroll
    for (int it = 0; it < 4; ++it) {
        int flat = tid + it * 256;   // 64 s-rows x 16 k-quads
        int s  = flat >> 4;
        int kq = flat & 15;
        bf16x4_t p = { (__bf16)T[(kq * 4 + 0) * 65 + s],
                       (__bf16)T[(kq * 4 + 1) * 65 + s],
                       (__bf16)T[(kq * 4 + 2) * 65 + s],
                       (__bf16)T[(kq * 4 + 3) * 65 + s] };
        *reinterpret_cast<bf16x4_t*>(
            encT + ((size_t)b * S_ + s0 + s) * H_ + k0 + kq * 4) = p;
    }
}

// W2b[h][k] = (bf16) W[h][H+k]
__global__ __launch_bounds__(256) void convw2_kernel(
    const float* __restrict__ W, __bf16* __restrict__ W2b)
{
    int idx = blockIdx.x * 256 + threadIdx.x;  // block covers one h row
    int h = idx >> 8, c4 = idx & 255;
    float4 vv = *reinterpret_cast<const float4*>(
        W + (size_t)h * (2 * H_) + H_ + c4 * 4);
    bf16x4_t p = { (__bf16)vv.x, (__bf16)vv.y, (__bf16)vv.z, (__bf16)vv.w };
    *reinterpret_cast<bf16x4_t*>(W2b + (size_t)h * H_ + c4 * 4) = p;
}

// ---------------------------------------------------------------------------
// m97-structure NT GEMM + fused tanh/v-dot epilogue:
//   D[h,s] = sum_k W2b[h,k] * encT[b,s,k];  logits[b,s] += sum_h v[h]*tanh(D+t1)
// 128x128 tile, BK=32, global_load_lds dwordx4 staging, ds_read_b128 frags.
// ---------------------------------------------------------------------------
__global__ __launch_bounds__(256) void energy_fast_kernel(
    const __bf16* __restrict__ W2b, const __bf16* __restrict__ encT,
    const float* __restrict__ t1, const float* __restrict__ v,
    float* __restrict__ logits)
{
    __shared__ __align__(16) __bf16 As[128 * 32];  // As[m][k], no pad (lds-DMA)
    __shared__ __align__(16) __bf16 Bs[128 * 32];  // Bs[n][k]

    const int b    = blockIdx.z;
    const int h0   = blockIdx.x * 128;
    const int s0   = blockIdx.y * 128;
    const int tid  = threadIdx.x;
    const int lane = tid & 63;
    const int wid  = tid >> 6;
    const int wm   = (wid & 1) * 64;
    const int wn   = (wid >> 1) * 64;
    const int quad = lane >> 4;
    const int l16  = lane & 15;

    // chunk c=tid covers tile elements [c*8, c*8+8): row c>>2, k-ofs (c&3)*8
    const __bf16* gA = W2b + (size_t)(h0 + (tid >> 2)) * H_ + (tid & 3) * 8;
    const __bf16* gB = encT + ((size_t)b * S_ + s0 + (tid >> 2)) * H_ + (tid & 3) * 8;
    __bf16* lA = As + tid * 8;
    __bf16* lB = Bs + tid * 8;

    f32x4_t acc[4][4] = {};

    for (int k0 = 0; k0 < H_; k0 += 32) {
        gl_lds16(gA,            lA);
        gl_lds16(gA + 64 * H_,  lA + 2048);
        gl_lds16(gB,            lB);
        gl_lds16(gB + 64 * H_,  lB + 2048);
        gA += 32; gB += 32;
        __syncthreads();

        bf16x8_t af[4], bfr[4];
        #pragma unroll
        for (int mi = 0; mi < 4; ++mi)
            af[mi] = *reinterpret_cast<const bf16x8_t*>(
                &As[(wm + mi * 16 + l16) * 32 + quad * 8]);
        #pragma unroll
        for (int ni = 0; ni < 4; ++ni)
            bfr[ni] = *reinterpret_cast<const bf16x8_t*>(
                &Bs[(wn + ni * 16 + l16) * 32 + quad * 8]);
        #pragma unroll
        for (int mi = 0; mi < 4; ++mi)
            #pragma unroll
            for (int ni = 0; ni < 4; ++ni)
                acc[mi][ni] = __builtin_amdgcn_mfma_f32_16x16x32_bf16(
                    af[mi], bfr[ni], acc[mi][ni], 0, 0, 0);
        __syncthreads();
    }

    // epilogue: logits[b,s] += sum over this tile's 128 h of v*tanh(.+t1)
    float tv[4][4], vv[4][4];
    #pragma unroll
    for (int mi = 0; mi < 4; ++mi)
        #pragma unroll
        for (int r = 0; r < 4; ++r) {
            int m = h0 + wm + mi * 16 + quad * 4 + r;  // D row = quad*4 + reg
            tv[mi][r] = t1[b * H_ + m];
            vv[mi][r] = v[m];
        }
    #pragma unroll
    for (int ni = 0; ni < 4; ++ni) {
        float p = 0.f;
        #pragma unroll
        for (int mi = 0; mi < 4; ++mi)
            #pragma unroll
            for (int r = 0; r < 4; ++r)
                p += vv[mi][r] * tanhf(acc[mi][ni][r] + tv[mi][r]);
        p += __shfl_xor(p, 16);
        p += __shfl_xor(p, 32);
        if (quad == 0)
            atomicAdd(&logits[(size_t)b * S_ + s0 + wn + ni * 16 + l16], p);
    }
}

// ---------------------------------------------------------------------------
// Fallback energy kernel (round-1 version) if workspace is too small for encT.
// ---------------------------------------------------------------------------
#define LDT 40
__global__ __launch_bounds__(256) void energy_slow_kernel(
    const float* __restrict__ enc, const float* __restrict__ W,
    const float* __restrict__ t1, const float* __restrict__ v,
    float* __restrict__ logits)
{
    __shared__ __align__(16) __bf16 As[128 * LDT];
    __shared__ __align__(16) __bf16 Bs[128 * LDT];
    const int b = blockIdx.z, h0 = blockIdx.x * 128, s0 = blockIdx.y * 128;
    const int tid = threadIdx.x, lane = tid & 63, wid = tid >> 6;
    const int wm = (wid & 1) * 64, wn = (wid >> 1) * 64;
    const int quad = lane >> 4, l16 = lane & 15;
    f32x4_t acc[4][4] = {};
    for (int k0 = 0; k0 < H_; k0 += 32) {
        #pragma unroll
        for (int i = 0; i < 4; ++i) {
            int flat = tid + i * 256;
            int m = flat >> 3, kq = flat & 7;
            const float4 wv = *reinterpret_cast<const float4*>(
                W + (size_t)(h0 + m) * (2 * H_) + H_ + k0 + kq * 4);
            bf16x4_t p = { (__bf16)wv.x, (__bf16)wv.y, (__bf16)wv.z, (__bf16)wv.w };
            *reinterpret_cast<bf16x4_t*>(&As[m * LDT + kq * 4]) = p;
        }
        #pragma unroll
        for (int i = 0; i < 4; ++i) {
            int flat = tid + i * 256;
            int kl = flat >> 5, nc = flat & 31;
            const float4 ev = *reinterpret_cast<const float4*>(
                enc + ((size_t)b * S_ + (k0 + kl)) * H_ + s0 + nc * 4);
            int n = nc * 4;
            Bs[(n + 0) * LDT + kl] = (__bf16)ev.x;
            Bs[(n + 1) * LDT + kl] = (__bf16)ev.y;
            Bs[(n + 2) * LDT + kl] = (__bf16)ev.z;
            Bs[(n + 3) * LDT + kl] = (__bf16)ev.w;
        }
        __syncthreads();
        bf16x8_t af[4], bfr[4];
        #pragma unroll
        for (int mi = 0; mi < 4; ++mi)
            af[mi] = *reinterpret_cast<const bf16x8_t*>(
                &As[(wm + mi * 16 + l16) * LDT + quad * 8]);
        #pragma unroll
        for (int ni = 0; ni < 4; ++ni)
            bfr[ni] = *reinterpret_cast<const bf16x8_t*>(
                &Bs[(wn + ni * 16 + l16) * LDT + quad * 8]);
        #pragma unroll
        for (int mi = 0; mi < 4; ++mi)
            #pragma unroll
            for (int ni = 0; ni < 4; ++ni)
                acc[mi][ni] = __builtin_amdgcn_mfma_f32_16x16x32_bf16(
                    af[mi], bfr[ni], acc[mi][ni], 0, 0, 0);
        __syncthreads();
    }
    float tv[4][4], vv[4][4];
    #pragma unroll
    for (int mi = 0; mi < 4; ++mi)
        #pragma unroll
        for (int r = 0; r < 4; ++r) {
            int m = h0 + wm + mi * 16 + quad * 4 + r;
            tv[mi][r] = t1[b * H_ + m];
            vv[mi][r] = v[m];
        }
    #pragma unroll
    for (int ni = 0; ni < 4; ++ni) {
        float p = 0.f;
        #pragma unroll
        for (int mi = 0; mi < 4; ++mi)
            #pragma unroll
            for (int r = 0; r < 4; ++r)
                p += vv[mi][r] * tanhf(acc[mi][ni][r] + tv[mi][r]);
        p += __shfl_xor(p, 16);
        p += __shfl_xor(p, 32);
        if (quad == 0)
            atomicAdd(&logits[(size_t)b * S_ + s0 + wn + ni * 16 + l16], p);
    }
}

// ---------------------------------------------------------------------------
__global__ __launch_bounds__(256) void softmax_kernel(
    const float* __restrict__ logits, float* __restrict__ scores)
{
    int b = blockIdx.x, tid = threadIdx.x;
    float x[4];
    float mx = -3.4e38f;
    #pragma unroll
    for (int i = 0; i < 4; ++i) {
        x[i] = logits[b * S_ + tid + i * 256];
        mx = fmaxf(mx, x[i]);
    }
    #pragma unroll
    for (int off = 1; off < 64; off <<= 1) mx = fmaxf(mx, __shfl_xor(mx, off));
    __shared__ float sm[4], ss[4];
    if ((tid & 63) == 0) sm[tid >> 6] = mx;
    __syncthreads();
    mx = fmaxf(fmaxf(sm[0], sm[1]), fmaxf(sm[2], sm[3]));
    float s = 0.f;
    #pragma unroll
    for (int i = 0; i < 4; ++i) {
        x[i] = expf(x[i] - mx);
        s += x[i];
    }
    #pragma unroll
    for (int off = 1; off < 64; off <<= 1) s += __shfl_xor(s, off);
    if ((tid & 63) == 0) ss[tid >> 6] = s;
    __syncthreads();
    float inv = 1.f / (ss[0] + ss[1] + ss[2] + ss[3]);
    #pragma unroll
    for (int i = 0; i < 4; ++i)
        scores[b * S_ + tid + i * 256] = x[i] * inv;
}

// ---------------------------------------------------------------------------
__global__ __launch_bounds__(256) void context_kernel(
    const float* __restrict__ enc, const float* __restrict__ scores,
    float* __restrict__ ctx)
{
    int b     = blockIdx.z;
    int h     = blockIdx.x * 256 + threadIdx.x;
    int sbase = blockIdx.y * 256;
    float acc = 0.f;
    for (int s = 0; s < 256; ++s) {
        acc += scores[b * S_ + sbase + s] *
               enc[((size_t)b * S_ + sbase + s) * H_ + h];
    }
    atomicAdd(&ctx[b * H_ + h], acc);
}

// ---------------------------------------------------------------------------
extern "C" void kernel_launch(void* const* d_in, const int* in_sizes, int n_in,
                              void* d_out, int out_size, void* d_ws, size_t ws_size,
                              hipStream_t stream)
{
    (void)in_sizes; (void)n_in; (void)out_size;
    const float* hidden = (const float*)d_in[0];
    const float* enc    = (const float*)d_in[1];
    const float* W      = (const float*)d_in[2];
    const float* bias   = (const float*)d_in[3];
    const float* v      = (const float*)d_in[4];

    float* out    = (float*)d_out;
    float* ctx    = out;             // [B,H]
    float* scores = out + B_ * H_;   // [B,S]

    // workspace layout
    float*  logits = (float*)d_ws;                         // B*S f32
    float*  t1     = logits + B_ * S_;                     // B*H f32
    __bf16* W2b    = (__bf16*)(t1 + B_ * H_);              // H*H bf16
    __bf16* encT   = W2b + (size_t)H_ * H_;                // B*S*H bf16
    const size_t need = (size_t)(B_ * S_ + B_ * H_) * 4 +
                        (size_t)H_ * H_ * 2 + (size_t)B_ * S_ * H_ * 2;

    hipMemsetAsync(logits, 0, (size_t)B_ * S_ * sizeof(float), stream);
    hipMemsetAsync(ctx, 0, (size_t)B_ * H_ * sizeof(float), stream);

    term1_kernel<<<dim3(H_ / 4, B_), 256, 0, stream>>>(hidden, W, bias, t1);

    if (ws_size >= need) {
        convw2_kernel<<<dim3(H_ * H_ / (256 * 4)), 256, 0, stream>>>(W, W2b);
        transpose_kernel<<<dim3(H_ / 64, S_ / 64, B_), 256, 0, stream>>>(enc, encT);
        energy_fast_kernel<<<dim3(H_ / 128, S_ / 128, B_), 256, 0, stream>>>(
            W2b, encT, t1, v, logits);
    } else {
        energy_slow_kernel<<<dim3(H_ / 128, S_ / 128, B_), 256, 0, stream>>>(
            enc, W, t1, v, logits);
    }

    softmax_kernel<<<B_, 256, 0, stream>>>(logits, scores);
    context_kernel<<<dim3(H_ / 256, S_ / 256, B_), 256, 0, stream>>>(
        enc, scores, ctx);
}

// Round 3
// 336.738 us; speedup vs baseline: 1.6692x; 1.0872x over previous
//
#include <hip/hip_runtime.h>
#include <hip/hip_bf16.h>
#include <math.h>

#define B_ 32
#define H_ 1024
#define S_ 1024

typedef __bf16 bf16x4_t __attribute__((ext_vector_type(4)));
typedef __bf16 bf16x8_t __attribute__((ext_vector_type(8)));
typedef float  f32x4_t  __attribute__((ext_vector_type(4)));
typedef float  f32x16_t __attribute__((ext_vector_type(16)));

// async global->LDS, 16B per lane; per-lane dest = base + lane*16 (contiguous).
__device__ __forceinline__ void gl_lds16(const void* g, void* l) {
    __builtin_amdgcn_global_load_lds(
        (const __attribute__((address_space(1))) uint32_t*)g,
        (__attribute__((address_space(3))) uint32_t*)l,
        16, 0, 0);
}

// tanh via hw exp2 + rcp (~5 VALU inst, ~1e-6 abs err; saturates correctly)
__device__ __forceinline__ float tanh_fast(float x) {
    float e = __builtin_amdgcn_exp2f(x * 2.885390081777927f);  // e^(2x)
    return 1.f - 2.f * __builtin_amdgcn_rcpf(e + 1.f);
}

// ---------------------------------------------------------------------------
// t1[b,h] = bias[h] + sum_k hidden[b,k]*W[h,k].  Wave per h-row: W row read
// once into registers, loop over all 32 batches (hidden is L2-hot).
// ---------------------------------------------------------------------------
__global__ __launch_bounds__(256) void term1_kernel(
    const float* __restrict__ hidden, const float* __restrict__ W,
    const float* __restrict__ bias, float* __restrict__ t1)
{
    int h    = blockIdx.x * 4 + (threadIdx.x >> 6);
    int lane = threadIdx.x & 63;
    const float4* wp = reinterpret_cast<const float4*>(W + (size_t)h * (2 * H_));
    float4 w0 = wp[lane], w1 = wp[lane + 64], w2 = wp[lane + 128], w3 = wp[lane + 192];
    float bh = bias[h];
    for (int b = 0; b < B_; ++b) {
        const float4* hp = reinterpret_cast<const float4*>(hidden + b * H_);
        float4 h0 = hp[lane], h1 = hp[lane + 64], h2 = hp[lane + 128], h3 = hp[lane + 192];
        float a = w0.x*h0.x + w0.y*h0.y + w0.z*h0.z + w0.w*h0.w
                + w1.x*h1.x + w1.y*h1.y + w1.z*h1.z + w1.w*h1.w
                + w2.x*h2.x + w2.y*h2.y + w2.z*h2.z + w2.w*h2.w
                + w3.x*h3.x + w3.y*h3.y + w3.z*h3.z + w3.w*h3.w;
        #pragma unroll
        for (int off = 1; off < 64; off <<= 1) a += __shfl_xor(a, off);
        if (lane == 0) t1[b * H_ + h] = a + bh;
    }
}

// ---------------------------------------------------------------------------
// prep: blocks [0,8192): encT[b][s][j] = (bf16) enc[b][j][s]  (64x64 LDS tiles)
//       blocks [8192,9216): W2b[h][k] = (bf16) W[h][H+k]
// ---------------------------------------------------------------------------
__global__ __launch_bounds__(256) void prep_kernel(
    const float* __restrict__ enc, const float* __restrict__ W,
    __bf16* __restrict__ encT, __bf16* __restrict__ W2b)
{
    __shared__ float T[64 * 65];
    const int idx = blockIdx.x;
    const int tid = threadIdx.x;
    if (idx < 8192) {
        const int b  = idx >> 8;
        const int k0 = ((idx >> 4) & 15) * 64;
        const int s0 = (idx & 15) * 64;
        #pragma unroll
        for (int it = 0; it < 4; ++it) {
            int flat = tid + it * 256;
            int r = flat >> 4, c4 = flat & 15;
            float4 vv = *reinterpret_cast<const float4*>(
                enc + ((size_t)b * S_ + k0 + r) * H_ + s0 + c4 * 4);
            T[r * 65 + c4 * 4 + 0] = vv.x;
            T[r * 65 + c4 * 4 + 1] = vv.y;
            T[r * 65 + c4 * 4 + 2] = vv.z;
            T[r * 65 + c4 * 4 + 3] = vv.w;
        }
        __syncthreads();
        #pragma unroll
        for (int it = 0; it < 4; ++it) {
            int flat = tid + it * 256;
            int s = flat >> 4, kq = flat & 15;
            bf16x4_t p = { (__bf16)T[(kq * 4 + 0) * 65 + s],
                           (__bf16)T[(kq * 4 + 1) * 65 + s],
                           (__bf16)T[(kq * 4 + 2) * 65 + s],
                           (__bf16)T[(kq * 4 + 3) * 65 + s] };
            *reinterpret_cast<bf16x4_t*>(
                encT + ((size_t)b * S_ + s0 + s) * H_ + k0 + kq * 4) = p;
        }
    } else {
        int i2 = (idx - 8192) * 1024 + tid * 4;  // one h-row per block
        int h = i2 >> 10, c = i2 & 1023;
        float4 vv = *reinterpret_cast<const float4*>(W + (size_t)h * (2 * H_) + H_ + c);
        bf16x4_t p = { (__bf16)vv.x, (__bf16)vv.y, (__bf16)vv.z, (__bf16)vv.w };
        *reinterpret_cast<bf16x4_t*>(W2b + (size_t)h * H_ + c) = p;
    }
}

// ---------------------------------------------------------------------------
// Energy GEMM v3: 128x128 tile, BK=64, 32x32x16 MFMA (2x2 per wave),
// XOR-swizzled LDS chunks (conflict-free reads, DMA-compatible writes),
// fused tanh/v-dot epilogue.
//   D[h,s] = sum_k W2b[h,k]*encT[b,s,k]; logits[b,s] += sum_h v[h]*tanh(D+t1)
// ---------------------------------------------------------------------------
#define BKE 64

__global__ __launch_bounds__(256) void energy_kernel(
    const __bf16* __restrict__ W2b, const __bf16* __restrict__ encT,
    const float* __restrict__ t1, const float* __restrict__ v,
    float* __restrict__ logits)
{
    __shared__ __align__(16) __bf16 As[128 * BKE];  // 16 KB
    __shared__ __align__(16) __bf16 Bs[128 * BKE];  // 16 KB

    const int b     = blockIdx.z;
    const int h0    = blockIdx.x * 128;
    const int s0    = blockIdx.y * 128;
    const int tid   = threadIdx.x;
    const int lane  = tid & 63;
    const int wid   = tid >> 6;
    const int wm    = (wid & 1) * 64;
    const int wn    = (wid >> 1) * 64;
    const int l32   = lane & 31;
    const int khalf = lane >> 5;   // k sub-offset selector (0/1 -> +0/+8)

    // staging map: flat f = tid + i*256; row = f>>3; lds chunk pos = f&7;
    // that slot receives global chunk c = (f&7) ^ (row&7)  (XOR swizzle).
    const __bf16* gAp[4]; const __bf16* gBp[4];
    __bf16* lAp[4]; __bf16* lBp[4];
    #pragma unroll
    for (int i = 0; i < 4; ++i) {
        int f   = tid + i * 256;
        int row = f >> 3;
        int c   = (f & 7) ^ (row & 7);
        gAp[i] = W2b + (size_t)(h0 + row) * H_ + c * 8;
        gBp[i] = encT + ((size_t)b * S_ + s0 + row) * H_ + c * 8;
        lAp[i] = As + f * 8;
        lBp[i] = Bs + f * 8;
    }

    f32x16_t acc[2][2] = {};

    for (int k0 = 0; k0 < H_; k0 += BKE) {
        #pragma unroll
        for (int i = 0; i < 4; ++i) gl_lds16(gAp[i] + k0, lAp[i]);
        #pragma unroll
        for (int i = 0; i < 4; ++i) gl_lds16(gBp[i] + k0, lBp[i]);
        __syncthreads();

        #pragma unroll
        for (int ks = 0; ks < 4; ++ks) {
            // frag wants chunk c = khalf + 2*ks of its row; swizzled pos:
            int p8 = (((khalf + 2 * ks) ^ (l32 & 7)) * 8);
            bf16x8_t a0 = *reinterpret_cast<const bf16x8_t*>(&As[(wm + l32) * BKE + p8]);
            bf16x8_t a1 = *reinterpret_cast<const bf16x8_t*>(&As[(wm + 32 + l32) * BKE + p8]);
            bf16x8_t b0 = *reinterpret_cast<const bf16x8_t*>(&Bs[(wn + l32) * BKE + p8]);
            bf16x8_t b1 = *reinterpret_cast<const bf16x8_t*>(&Bs[(wn + 32 + l32) * BKE + p8]);
            acc[0][0] = __builtin_amdgcn_mfma_f32_32x32x16_bf16(a0, b0, acc[0][0], 0, 0, 0);
            acc[0][1] = __builtin_amdgcn_mfma_f32_32x32x16_bf16(a0, b1, acc[0][1], 0, 0, 0);
            acc[1][0] = __builtin_amdgcn_mfma_f32_32x32x16_bf16(a1, b0, acc[1][0], 0, 0, 0);
            acc[1][1] = __builtin_amdgcn_mfma_f32_32x32x16_bf16(a1, b1, acc[1][1], 0, 0, 0);
        }
        __syncthreads();
    }

    // epilogue: 32x32 C/D layout: col = lane&31, row = (r&3)+8*(r>>2)+4*(lane>>5)
    float pn0 = 0.f, pn1 = 0.f;
    #pragma unroll
    for (int mt = 0; mt < 2; ++mt)
        #pragma unroll
        for (int r = 0; r < 16; ++r) {
            int row = wm + mt * 32 + (r & 3) + 8 * (r >> 2) + 4 * khalf;
            int h = h0 + row;
            float tv = t1[b * H_ + h];
            float vv = v[h];
            pn0 += vv * tanh_fast(acc[mt][0][r] + tv);
            pn1 += vv * tanh_fast(acc[mt][1][r] + tv);
        }
    pn0 += __shfl_xor(pn0, 32);
    pn1 += __shfl_xor(pn1, 32);
    if (lane < 32) {
        atomicAdd(&logits[(size_t)b * S_ + s0 + wn + l32], pn0);
        atomicAdd(&logits[(size_t)b * S_ + s0 + wn + 32 + l32], pn1);
    }
}

// ---------------------------------------------------------------------------
__global__ __launch_bounds__(256) void softmax_kernel(
    const float* __restrict__ logits, float* __restrict__ scores)
{
    int b = blockIdx.x, tid = threadIdx.x;
    float x[4];
    float mx = -3.4e38f;
    #pragma unroll
    for (int i = 0; i < 4; ++i) {
        x[i] = logits[b * S_ + tid + i * 256];
        mx = fmaxf(mx, x[i]);
    }
    #pragma unroll
    for (int off = 1; off < 64; off <<= 1) mx = fmaxf(mx, __shfl_xor(mx, off));
    __shared__ float sm[4], ss[4];
    if ((tid & 63) == 0) sm[tid >> 6] = mx;
    __syncthreads();
    mx = fmaxf(fmaxf(sm[0], sm[1]), fmaxf(sm[2], sm[3]));
    float s = 0.f;
    #pragma unroll
    for (int i = 0; i < 4; ++i) {
        x[i] = expf(x[i] - mx);
        s += x[i];
    }
    #pragma unroll
    for (int off = 1; off < 64; off <<= 1) s += __shfl_xor(s, off);
    if ((tid & 63) == 0) ss[tid >> 6] = s;
    __syncthreads();
    float inv = 1.f / (ss[0] + ss[1] + ss[2] + ss[3]);
    #pragma unroll
    for (int i = 0; i < 4; ++i)
        scores[b * S_ + tid + i * 256] = x[i] * inv;
}

// ---------------------------------------------------------------------------
// context[b,h] = sum_s scores[b,s]*enc[b,s,h] = sum_s scores[b,s]*encT[b,h,s].
// Wave per (b,h): encT row is s-contiguous bf16 -> 16B loads; direct store.
// ---------------------------------------------------------------------------
__global__ __launch_bounds__(256) void context_kernel(
    const __bf16* __restrict__ encT, const float* __restrict__ scores,
    float* __restrict__ ctx)
{
    int gw   = blockIdx.x * 4 + (threadIdx.x >> 6);  // 0 .. B*H-1
    int b    = gw >> 10;
    int h    = gw & 1023;
    int lane = threadIdx.x & 63;
    const __bf16* rp = encT + ((size_t)b * S_ + h) * H_;
    const float*  sp = scores + (size_t)b * S_;
    float acc = 0.f;
    #pragma unroll
    for (int c = 0; c < 2; ++c) {
        int s8 = (lane + c * 64) * 8;
        bf16x8_t ev = *reinterpret_cast<const bf16x8_t*>(&rp[s8]);
        float4 sa = *reinterpret_cast<const float4*>(&sp[s8]);
        float4 sb = *reinterpret_cast<const float4*>(&sp[s8 + 4]);
        acc += (float)ev[0]*sa.x + (float)ev[1]*sa.y + (float)ev[2]*sa.z + (float)ev[3]*sa.w
             + (float)ev[4]*sb.x + (float)ev[5]*sb.y + (float)ev[6]*sb.z + (float)ev[7]*sb.w;
    }
    #pragma unroll
    for (int off = 1; off < 64; off <<= 1) acc += __shfl_xor(acc, off);
    if (lane == 0) ctx[(size_t)b * H_ + h] = acc;
}

// ---------------------------------------------------------------------------
extern "C" void kernel_launch(void* const* d_in, const int* in_sizes, int n_in,
                              void* d_out, int out_size, void* d_ws, size_t ws_size,
                              hipStream_t stream)
{
    (void)in_sizes; (void)n_in; (void)out_size; (void)ws_size;
    const float* hidden = (const float*)d_in[0];
    const float* enc    = (const float*)d_in[1];
    const float* W      = (const float*)d_in[2];
    const float* bias   = (const float*)d_in[3];
    const float* v      = (const float*)d_in[4];

    float* out    = (float*)d_out;
    float* ctx    = out;             // [B,H]
    float* scores = out + B_ * H_;   // [B,S]

    float*  logits = (float*)d_ws;                // B*S f32
    float*  t1     = logits + B_ * S_;            // B*H f32
    __bf16* W2b    = (__bf16*)(t1 + B_ * H_);     // H*H bf16
    __bf16* encT   = W2b + (size_t)H_ * H_;       // B*S*H bf16 (16B-aligned)

    hipMemsetAsync(logits, 0, (size_t)B_ * S_ * sizeof(float), stream);

    term1_kernel<<<dim3(H_ / 4), 256, 0, stream>>>(hidden, W, bias, t1);
    prep_kernel<<<dim3(8192 + 1024), 256, 0, stream>>>(enc, W, encT, W2b);
    energy_kernel<<<dim3(H_ / 128, S_ / 128, B_), 256, 0, stream>>>(
        W2b, encT, t1, v, logits);
    softmax_kernel<<<B_, 256, 0, stream>>>(logits, scores);
    context_kernel<<<dim3(B_ * H_ / 4), 256, 0, stream>>>(encT, scores, ctx);
}

// Round 4
// 328.312 us; speedup vs baseline: 1.7121x; 1.0257x over previous
//
#include <hip/hip_runtime.h>
#include <hip/hip_bf16.h>
#include <math.h>

#define B_ 32
#define H_ 1024
#define S_ 1024

typedef __bf16 bf16x4_t __attribute__((ext_vector_type(4)));
typedef __bf16 bf16x8_t __attribute__((ext_vector_type(8)));
typedef float  f32x4_t  __attribute__((ext_vector_type(4)));
typedef float  f32x16_t __attribute__((ext_vector_type(16)));

// async global->LDS, 16B per lane; per-lane dest = base + lane*16 (contiguous).
__device__ __forceinline__ void gl_lds16(const void* g, void* l) {
    __builtin_amdgcn_global_load_lds(
        (const __attribute__((address_space(1))) uint32_t*)g,
        (__attribute__((address_space(3))) uint32_t*)l,
        16, 0, 0);
}

// tanh via hw exp2 + rcp (~5 VALU inst, ~1e-6 abs err; saturates correctly)
__device__ __forceinline__ float tanh_fast(float x) {
    float e = __builtin_amdgcn_exp2f(x * 2.885390081777927f);  // e^(2x)
    return 1.f - 2.f * __builtin_amdgcn_rcpf(e + 1.f);
}

// ---------------------------------------------------------------------------
// prep (one dispatch, 3 block roles):
//  [0,8192):      encT[b][s][j] = (bf16) enc[b][j][s]   (64x64 LDS tiles)
//  [8192,9216):   W2b[h][k] = (bf16) W[h][H+k]
//  [9216,9472):   t1[b,h] = bias[h] + sum_k hidden[b,k]*W[h,k]  (wave per h)
// ---------------------------------------------------------------------------
__global__ __launch_bounds__(256) void prep_kernel(
    const float* __restrict__ enc, const float* __restrict__ W,
    const float* __restrict__ hidden, const float* __restrict__ bias,
    __bf16* __restrict__ encT, __bf16* __restrict__ W2b,
    float* __restrict__ t1)
{
    __shared__ float T[64 * 65];
    const int idx = blockIdx.x;
    const int tid = threadIdx.x;
    if (idx < 8192) {
        const int b  = idx >> 8;
        const int k0 = ((idx >> 4) & 15) * 64;
        const int s0 = (idx & 15) * 64;
        #pragma unroll
        for (int it = 0; it < 4; ++it) {
            int flat = tid + it * 256;          // 64 rows x 16 float4
            int r = flat >> 4, c4 = flat & 15;
            float4 vv = *reinterpret_cast<const float4*>(
                enc + ((size_t)b * S_ + k0 + r) * H_ + s0 + c4 * 4);
            T[r * 65 + c4 * 4 + 0] = vv.x;
            T[r * 65 + c4 * 4 + 1] = vv.y;
            T[r * 65 + c4 * 4 + 2] = vv.z;
            T[r * 65 + c4 * 4 + 3] = vv.w;
        }
        __syncthreads();
        #pragma unroll
        for (int it = 0; it < 2; ++it) {
            int flat = tid + it * 256;          // 64 s-rows x 8 k-octets
            int s = flat >> 3, ko = flat & 7;
            bf16x8_t p;
            #pragma unroll
            for (int j = 0; j < 8; ++j)
                p[j] = (__bf16)T[(ko * 8 + j) * 65 + s];
            *reinterpret_cast<bf16x8_t*>(
                encT + ((size_t)b * S_ + s0 + s) * H_ + k0 + ko * 8) = p;
        }
    } else if (idx < 9216) {
        int i2 = (idx - 8192) * 1024 + tid * 4;  // one h-row per block
        int h = i2 >> 10, c = i2 & 1023;
        float4 vv = *reinterpret_cast<const float4*>(W + (size_t)h * (2 * H_) + H_ + c);
        bf16x4_t p = { (__bf16)vv.x, (__bf16)vv.y, (__bf16)vv.z, (__bf16)vv.w };
        *reinterpret_cast<bf16x4_t*>(W2b + (size_t)h * H_ + c) = p;
    } else {
        int h    = (idx - 9216) * 4 + (tid >> 6);
        int lane = tid & 63;
        const float4* wp = reinterpret_cast<const float4*>(W + (size_t)h * (2 * H_));
        float4 w0 = wp[lane], w1 = wp[lane + 64], w2 = wp[lane + 128], w3 = wp[lane + 192];
        float bh = bias[h];
        for (int b = 0; b < B_; ++b) {
            const float4* hp = reinterpret_cast<const float4*>(hidden + b * H_);
            float4 h0 = hp[lane], h1 = hp[lane + 64], h2 = hp[lane + 128], h3 = hp[lane + 192];
            float a = w0.x*h0.x + w0.y*h0.y + w0.z*h0.z + w0.w*h0.w
                    + w1.x*h1.x + w1.y*h1.y + w1.z*h1.z + w1.w*h1.w
                    + w2.x*h2.x + w2.y*h2.y + w2.z*h2.z + w2.w*h2.w
                    + w3.x*h3.x + w3.y*h3.y + w3.z*h3.z + w3.w*h3.w;
            #pragma unroll
            for (int off = 1; off < 64; off <<= 1) a += __shfl_xor(a, off);
            if (lane == 0) t1[b * H_ + h] = a + bh;
        }
    }
}

// ---------------------------------------------------------------------------
// Energy GEMM v4: 128x128 tile, BK=32, 32x32x16 MFMA (2x2/wave), DOUBLE-
// buffered LDS with next-tile loads issued at the top of the compute window
// (latency hidden under compute; single barrier per iter). Conflict-free
// chunk swizzle: store chunk c at pos c^((row>>3)&3); 32 lanes' 16B reads
// cover 32 distinct 512B-aliased slots.
//   D[h,s] = sum_k W2b[h,k]*encT[b,s,k]; logits[b,s] += sum_h v[h]*tanh(D+t1)
// ---------------------------------------------------------------------------
#define BK2 32

__global__ __launch_bounds__(256) void energy_kernel(
    const __bf16* __restrict__ W2b, const __bf16* __restrict__ encT,
    const float* __restrict__ t1, const float* __restrict__ v,
    float* __restrict__ logits)
{
    __shared__ __align__(16) __bf16 As[2][128 * BK2];  // 2 x 8 KB
    __shared__ __align__(16) __bf16 Bs[2][128 * BK2];  // 2 x 8 KB

    const int b     = blockIdx.z;
    const int h0    = blockIdx.x * 128;
    const int s0    = blockIdx.y * 128;
    const int tid   = threadIdx.x;
    const int lane  = tid & 63;
    const int wid   = tid >> 6;
    const int wm    = (wid & 1) * 64;
    const int wn    = (wid >> 1) * 64;
    const int l32   = lane & 31;
    const int khalf = lane >> 5;

    // staging: flat f = tid + i*256 (512 chunks/tile); row = f>>2, pos = f&3;
    // slot receives global chunk c = pos ^ ((row>>3)&3).
    const __bf16* gA[2]; const __bf16* gB[2]; int lofs[2];
    #pragma unroll
    for (int i = 0; i < 2; ++i) {
        int f   = tid + i * 256;
        int row = f >> 2;
        int c   = (f & 3) ^ ((row >> 3) & 3);
        gA[i]   = W2b + (size_t)(h0 + row) * H_ + c * 8;
        gB[i]   = encT + ((size_t)b * S_ + s0 + row) * H_ + c * 8;
        lofs[i] = f * 8;
    }

    // prologue: stage tile 0 into buffer 0
    #pragma unroll
    for (int i = 0; i < 2; ++i) {
        gl_lds16(gA[i], &As[0][lofs[i]]);
        gl_lds16(gB[i], &Bs[0][lofs[i]]);
    }
    __syncthreads();

    f32x16_t acc[2][2] = {};
    const int pswz = (l32 >> 3) & 3;

    for (int it = 0; it < H_ / BK2; ++it) {
        const int cur = it & 1, nxt = cur ^ 1;
        if (it < H_ / BK2 - 1) {
            const int k1 = (it + 1) * BK2;
            #pragma unroll
            for (int i = 0; i < 2; ++i) {
                gl_lds16(gA[i] + k1, &As[nxt][lofs[i]]);
                gl_lds16(gB[i] + k1, &Bs[nxt][lofs[i]]);
            }
        }
        #pragma unroll
        for (int ks = 0; ks < 2; ++ks) {
            int p8 = ((khalf + 2 * ks) ^ pswz) * 8;
            bf16x8_t a0 = *reinterpret_cast<const bf16x8_t*>(&As[cur][(wm      + l32) * BK2 + p8]);
            bf16x8_t a1 = *reinterpret_cast<const bf16x8_t*>(&As[cur][(wm + 32 + l32) * BK2 + p8]);
            bf16x8_t b0 = *reinterpret_cast<const bf16x8_t*>(&Bs[cur][(wn      + l32) * BK2 + p8]);
            bf16x8_t b1 = *reinterpret_cast<const bf16x8_t*>(&Bs[cur][(wn + 32 + l32) * BK2 + p8]);
            acc[0][0] = __builtin_amdgcn_mfma_f32_32x32x16_bf16(a0, b0, acc[0][0], 0, 0, 0);
            acc[0][1] = __builtin_amdgcn_mfma_f32_32x32x16_bf16(a0, b1, acc[0][1], 0, 0, 0);
            acc[1][0] = __builtin_amdgcn_mfma_f32_32x32x16_bf16(a1, b0, acc[1][0], 0, 0, 0);
            acc[1][1] = __builtin_amdgcn_mfma_f32_32x32x16_bf16(a1, b1, acc[1][1], 0, 0, 0);
        }
        __syncthreads();
    }

    // epilogue: 32x32 C/D: col = lane&31, row = (r&3)+8*(r>>2)+4*(lane>>5)
    float pn0 = 0.f, pn1 = 0.f;
    #pragma unroll
    for (int mt = 0; mt < 2; ++mt)
        #pragma unroll
        for (int r = 0; r < 16; ++r) {
            int row = wm + mt * 32 + (r & 3) + 8 * (r >> 2) + 4 * khalf;
            int h = h0 + row;
            float tv = t1[b * H_ + h];
            float vv = v[h];
            pn0 += vv * tanh_fast(acc[mt][0][r] + tv);
            pn1 += vv * tanh_fast(acc[mt][1][r] + tv);
        }
    pn0 += __shfl_xor(pn0, 32);
    pn1 += __shfl_xor(pn1, 32);
    if (lane < 32) {
        atomicAdd(&logits[(size_t)b * S_ + s0 + wn + l32], pn0);
        atomicAdd(&logits[(size_t)b * S_ + s0 + wn + 32 + l32], pn1);
    }
}

// ---------------------------------------------------------------------------
// Fused softmax + context. Each block: softmax of logits[b,:] (redundant per
// h-chunk, trivial), scores kept in LDS; then context for 64 h rows.
// blockIdx.x==0 also writes scores to global.
// ---------------------------------------------------------------------------
__global__ __launch_bounds__(256) void ctx_kernel(
    const __bf16* __restrict__ encT, const float* __restrict__ logits,
    float* __restrict__ scores, float* __restrict__ ctx)
{
    __shared__ float sc[1024];
    __shared__ float red[8];
    const int b    = blockIdx.y;
    const int hb   = blockIdx.x * 64;
    const int tid  = threadIdx.x;
    const int lane = tid & 63;
    const int w    = tid >> 6;

    float4 lg = *reinterpret_cast<const float4*>(logits + (size_t)b * S_ + tid * 4);
    float mx = fmaxf(fmaxf(lg.x, lg.y), fmaxf(lg.z, lg.w));
    #pragma unroll
    for (int off = 1; off < 64; off <<= 1) mx = fmaxf(mx, __shfl_xor(mx, off));
    if (lane == 0) red[w] = mx;
    __syncthreads();
    mx = fmaxf(fmaxf(red[0], red[1]), fmaxf(red[2], red[3]));
    const float L2E = 1.44269504088896f;
    float e0 = __builtin_amdgcn_exp2f((lg.x - mx) * L2E);
    float e1 = __builtin_amdgcn_exp2f((lg.y - mx) * L2E);
    float e2 = __builtin_amdgcn_exp2f((lg.z - mx) * L2E);
    float e3 = __builtin_amdgcn_exp2f((lg.w - mx) * L2E);
    float s = e0 + e1 + e2 + e3;
    #pragma unroll
    for (int off = 1; off < 64; off <<= 1) s += __shfl_xor(s, off);
    if (lane == 0) red[4 + w] = s;
    __syncthreads();
    float inv = 1.f / (red[4] + red[5] + red[6] + red[7]);
    float4 sv = { e0 * inv, e1 * inv, e2 * inv, e3 * inv };
    *reinterpret_cast<float4*>(&sc[tid * 4]) = sv;
    if (blockIdx.x == 0)
        *reinterpret_cast<float4*>(scores + (size_t)b * S_ + tid * 4) = sv;
    __syncthreads();

    // context: wave w handles rows hb + w*16 .. +16
    for (int r = 0; r < 16; ++r) {
        int h = hb + w * 16 + r;
        const __bf16* rp = encT + ((size_t)b * S_ + h) * H_;  // encT[b][h][s]
        float acc = 0.f;
        #pragma unroll
        for (int c = 0; c < 2; ++c) {
            int s8 = (lane + c * 64) * 8;
            bf16x8_t ev = *reinterpret_cast<const bf16x8_t*>(&rp[s8]);
            float4 sa = *reinterpret_cast<const float4*>(&sc[s8]);
            float4 sb = *reinterpret_cast<const float4*>(&sc[s8 + 4]);
            acc += (float)ev[0]*sa.x + (float)ev[1]*sa.y + (float)ev[2]*sa.z + (float)ev[3]*sa.w
                 + (float)ev[4]*sb.x + (float)ev[5]*sb.y + (float)ev[6]*sb.z + (float)ev[7]*sb.w;
        }
        #pragma unroll
        for (int off = 1; off < 64; off <<= 1) acc += __shfl_xor(acc, off);
        if (lane == 0) ctx[(size_t)b * H_ + h] = acc;
    }
}

// ---------------------------------------------------------------------------
extern "C" void kernel_launch(void* const* d_in, const int* in_sizes, int n_in,
                              void* d_out, int out_size, void* d_ws, size_t ws_size,
                              hipStream_t stream)
{
    (void)in_sizes; (void)n_in; (void)out_size; (void)ws_size;
    const float* hidden = (const float*)d_in[0];
    const float* enc    = (const float*)d_in[1];
    const float* W      = (const float*)d_in[2];
    const float* bias   = (const float*)d_in[3];
    const float* v      = (const float*)d_in[4];

    float* out    = (float*)d_out;
    float* ctx    = out;             // [B,H]
    float* scores = out + B_ * H_;   // [B,S]

    float*  logits = (float*)d_ws;                // B*S f32
    float*  t1     = logits + B_ * S_;            // B*H f32
    __bf16* W2b    = (__bf16*)(t1 + B_ * H_);     // H*H bf16
    __bf16* encT   = W2b + (size_t)H_ * H_;       // B*S*H bf16 (16B-aligned)

    hipMemsetAsync(logits, 0, (size_t)B_ * S_ * sizeof(float), stream);

    prep_kernel<<<dim3(8192 + 1024 + 256), 256, 0, stream>>>(
        enc, W, hidden, bias, encT, W2b, t1);
    energy_kernel<<<dim3(H_ / 128, S_ / 128, B_), 256, 0, stream>>>(
        W2b, encT, t1, v, logits);
    ctx_kernel<<<dim3(H_ / 64, B_), 256, 0, stream>>>(encT, logits, scores, ctx);
}

// Round 5
// 312.862 us; speedup vs baseline: 1.7966x; 1.0494x over previous
//
#include <hip/hip_runtime.h>
#include <hip/hip_bf16.h>
#include <math.h>

#define B_ 32
#define H_ 1024
#define S_ 1024

typedef float  f32x4_t  __attribute__((ext_vector_type(4)));
typedef float  f32x16_t __attribute__((ext_vector_type(16)));
typedef long long i64;
typedef i64 i64x2 __attribute__((ext_vector_type(2)));
typedef unsigned char u8;

// async global->LDS, 16B per lane; LDS dest = wave-uniform base + lane*16.
__device__ __forceinline__ void gl_lds16(const void* g, void* l) {
    __builtin_amdgcn_global_load_lds(
        (const __attribute__((address_space(1))) unsigned int*)g,
        (__attribute__((address_space(3))) unsigned int*)l, 16, 0, 0);
}

// tanh via hw exp2 + rcp (~5 VALU inst, ~1e-6 abs err; saturates correctly)
__device__ __forceinline__ float tanh_fast(float x) {
    float e = __builtin_amdgcn_exp2f(x * 2.885390081777927f);  // e^(2x)
    return 1.f - 2.f * __builtin_amdgcn_rcpf(e + 1.f);
}

// fp8 tile k-permutation within a 32-k group: swap bits 3<->4 (involution).
// stored pos p <-> true k: chunk c=p>>4 holds khalf=c data for BOTH k-steps:
// bytes [0..7]=ks0, [8..15]=ks1  ->  one 16B LDS read = 2 MFMA fragments.
__device__ __forceinline__ int kperm(int k) {
    return (k & ~24) | ((k & 8) << 1) | ((k & 16) >> 1);
}

// ---------------------------------------------------------------------------
// prep (one dispatch, 3 roles):
//  [0,8192):     encF8[b][kt][s][32B] = e4m3(enc[b][k][s]), k-permuted/tiled
//  [8192,9216):  W2f8[kt][h][32B] = e4m3(64 * W[h][H+k]), k-permuted/tiled
//                 (+ zero 64 floats of logits/ctx per block)
//  [9216,9472):  t1[b,h] = bias[h] + sum_k hidden[b,k]*W[h,k]  (wave per h)
// ---------------------------------------------------------------------------
__global__ __launch_bounds__(256) void prep_kernel(
    const float* __restrict__ enc, const float* __restrict__ W,
    const float* __restrict__ hidden, const float* __restrict__ bias,
    u8* __restrict__ encF8, u8* __restrict__ W2f8,
    float* __restrict__ t1, float* __restrict__ logits,
    float* __restrict__ ctx)
{
    __shared__ float T[64 * 65];
    const int idx = blockIdx.x;
    const int tid = threadIdx.x;
    if (idx < 8192) {
        const int b  = idx >> 8;
        const int k0 = ((idx >> 4) & 15) * 64;   // reduction-axis tile base
        const int s0 = (idx & 15) * 64;
        #pragma unroll
        for (int it = 0; it < 4; ++it) {
            int flat = tid + it * 256;           // 64 rows x 16 float4
            int r = flat >> 4, c4 = flat & 15;
            float4 vv = *reinterpret_cast<const float4*>(
                enc + ((size_t)b * S_ + k0 + r) * H_ + s0 + c4 * 4);
            T[r * 65 + c4 * 4 + 0] = vv.x;
            T[r * 65 + c4 * 4 + 1] = vv.y;
            T[r * 65 + c4 * 4 + 2] = vv.z;
            T[r * 65 + c4 * 4 + 3] = vv.w;
        }
        __syncthreads();
        // each thread: one 16B chunk (s, kt_local, c) of the fp8 tiled layout
        {
            int c   = tid & 1;          // khalf chunk
            int ktl = (tid >> 1) & 1;   // which 32-k subtile of the 64-k tile
            int s   = tid >> 2;         // 0..63
            int w4[4];
            #pragma unroll
            for (int w = 0; w < 4; ++w) {
                float f[4];
                #pragma unroll
                for (int u = 0; u < 4; ++u) {
                    int i   = w * 4 + u;               // byte in chunk
                    int k32 = 16 * (i >> 3) + 8 * c + (i & 7);  // true k in 32-grp
                    f[u] = T[(ktl * 32 + k32) * 65 + s];
                }
                int pw = __builtin_amdgcn_cvt_pk_fp8_f32(f[0], f[1], 0, false);
                pw     = __builtin_amdgcn_cvt_pk_fp8_f32(f[2], f[3], pw, true);
                w4[w] = pw;
            }
            int4 payload = { w4[0], w4[1], w4[2], w4[3] };
            *reinterpret_cast<int4*>(
                encF8 + (size_t)b * 1048576 + (size_t)((k0 >> 5) + ktl) * 32768
                + (size_t)(s0 + s) * 32 + c * 16) = payload;
        }
    } else if (idx < 9216) {
        int h = idx - 8192;  // one h row
        if (tid < 64) {      // zero logits (first 32768) then ctx (next 32768)
            int z = h * 64 + tid;
            if (z < B_ * S_) logits[z] = 0.f;
            else             ctx[z - B_ * S_] = 0.f;
        }
        int kt = tid >> 3;            // 0..31
        int q  = tid & 7;             // dest 4-byte word in 32B chunk
        int src = kperm(q * 4);       // contiguous 4 source floats
        float4 wv = *reinterpret_cast<const float4*>(
            W + (size_t)h * (2 * H_) + H_ + kt * 32 + src);
        int pw = __builtin_amdgcn_cvt_pk_fp8_f32(wv.x * 64.f, wv.y * 64.f, 0, false);
        pw     = __builtin_amdgcn_cvt_pk_fp8_f32(wv.z * 64.f, wv.w * 64.f, pw, true);
        *reinterpret_cast<int*>(W2f8 + (size_t)kt * 32768 + (size_t)h * 32 + q * 4) = pw;
    } else {
        int h    = (idx - 9216) * 4 + (tid >> 6);
        int lane = tid & 63;
        const float4* wp = reinterpret_cast<const float4*>(W + (size_t)h * (2 * H_));
        float4 w0 = wp[lane], w1 = wp[lane + 64], w2 = wp[lane + 128], w3 = wp[lane + 192];
        float bh = bias[h];
        for (int b = 0; b < B_; ++b) {
            const float4* hp = reinterpret_cast<const float4*>(hidden + b * H_);
            float4 h0 = hp[lane], h1 = hp[lane + 64], h2 = hp[lane + 128], h3 = hp[lane + 192];
            float a = w0.x*h0.x + w0.y*h0.y + w0.z*h0.z + w0.w*h0.w
                    + w1.x*h1.x + w1.y*h1.y + w1.z*h1.z + w1.w*h1.w
                    + w2.x*h2.x + w2.y*h2.y + w2.z*h2.z + w2.w*h2.w
                    + w3.x*h3.x + w3.y*h3.y + w3.z*h3.z + w3.w*h3.w;
            #pragma unroll
            for (int off = 1; off < 64; off <<= 1) a += __shfl_xor(a, off);
            if (lane == 0) t1[b * H_ + h] = a + bh;
        }
    }
}

// ---------------------------------------------------------------------------
// Energy GEMM v5 (fp8 e4m3): 128x128 tile, BK=32, mfma_f32_32x32x16_fp8_fp8
// (2x2 per wave), double-buffered LDS (2 x 4KB per operand). One 16B LDS read
// per fragment-pair covers both k-steps. LDS slot map: window hi=row>>5 (1KB,
// staged by wave hi), local slot = 4*(row&7) + ((row>>3)&3) + 32*khalf -> the
// 32 lanes of a fragment read hit 32 distinct 16B slots mod 512B (round-4-
// verified zero-conflict criterion). W2 pre-scaled x64; 1/64 in epilogue.
//   D[h,s] = sum_k W2[h,k]*enc[b,k,s]; logits[b,s] += sum_h v[h]*tanh(D+t1)
// ---------------------------------------------------------------------------
__global__ __launch_bounds__(256) void energy_kernel(
    const u8* __restrict__ W2f8, const u8* __restrict__ encF8,
    const float* __restrict__ t1, const float* __restrict__ v,
    float* __restrict__ logits)
{
    __shared__ __align__(16) u8 As[2][4096];
    __shared__ __align__(16) u8 Bs[2][4096];

    const int b     = blockIdx.z;
    const int h0    = blockIdx.x * 128;
    const int s0    = blockIdx.y * 128;
    const int tid   = threadIdx.x;
    const int lane  = tid & 63;
    const int wid   = tid >> 6;
    const int wm    = (wid & 1) * 64;
    const int wn    = (wid >> 1) * 64;
    const int l32   = lane & 31;
    const int khalf = lane >> 5;

    // staging: wave wid stages window wid (rows 32*wid..+31); lane's slot is
    // lane itself -> LDS dest = base + tid*16. Inverse slot map gives row:
    const int rowl = ((lane & 3) << 3) | ((lane >> 2) & 7);
    const int row  = (wid << 5) | rowl;
    const int cch  = lane >> 5;  // chunk (khalf plane)
    const size_t gofsA = (size_t)(h0 + row) * 32 + cch * 16;
    const size_t gofsB = (size_t)b * 1048576 + (size_t)(s0 + row) * 32 + cch * 16;

    // prologue: stage k-tile 0 into buffer 0
    gl_lds16(W2f8 + gofsA, &As[0][tid * 16]);
    gl_lds16(encF8 + gofsB, &Bs[0][tid * 16]);
    __syncthreads();

    f32x16_t acc[2][2] = {};
    const int sl  = ((((l32 & 7) << 2) | (l32 >> 3)) | (khalf << 5)) * 16;
    const int wAo = (wm >> 5) * 1024;   // window byte offset of first m-row grp
    const int wBo = (wn >> 5) * 1024;

    for (int kt = 0; kt < 32; ++kt) {
        const int cur = kt & 1, nxt = cur ^ 1;
        if (kt < 31) {
            gl_lds16(W2f8 + gofsA + (size_t)(kt + 1) * 32768, &As[nxt][tid * 16]);
            gl_lds16(encF8 + gofsB + (size_t)(kt + 1) * 32768, &Bs[nxt][tid * 16]);
        }
        i64x2 a0 = *reinterpret_cast<const i64x2*>(&As[cur][wAo + sl]);
        i64x2 a1 = *reinterpret_cast<const i64x2*>(&As[cur][wAo + 1024 + sl]);
        i64x2 b0 = *reinterpret_cast<const i64x2*>(&Bs[cur][wBo + sl]);
        i64x2 b1 = *reinterpret_cast<const i64x2*>(&Bs[cur][wBo + 1024 + sl]);
        acc[0][0] = __builtin_amdgcn_mfma_f32_32x32x16_fp8_fp8(a0.x, b0.x, acc[0][0], 0, 0, 0);
        acc[0][1] = __builtin_amdgcn_mfma_f32_32x32x16_fp8_fp8(a0.x, b1.x, acc[0][1], 0, 0, 0);
        acc[1][0] = __builtin_amdgcn_mfma_f32_32x32x16_fp8_fp8(a1.x, b0.x, acc[1][0], 0, 0, 0);
        acc[1][1] = __builtin_amdgcn_mfma_f32_32x32x16_fp8_fp8(a1.x, b1.x, acc[1][1], 0, 0, 0);
        acc[0][0] = __builtin_amdgcn_mfma_f32_32x32x16_fp8_fp8(a0.y, b0.y, acc[0][0], 0, 0, 0);
        acc[0][1] = __builtin_amdgcn_mfma_f32_32x32x16_fp8_fp8(a0.y, b1.y, acc[0][1], 0, 0, 0);
        acc[1][0] = __builtin_amdgcn_mfma_f32_32x32x16_fp8_fp8(a1.y, b0.y, acc[1][0], 0, 0, 0);
        acc[1][1] = __builtin_amdgcn_mfma_f32_32x32x16_fp8_fp8(a1.y, b1.y, acc[1][1], 0, 0, 0);
        __syncthreads();
    }

    // epilogue: 32x32 C/D: col = lane&31, row = (r&3)+8*(r>>2)+4*(lane>>5)
    float pn0 = 0.f, pn1 = 0.f;
    #pragma unroll
    for (int mt = 0; mt < 2; ++mt)
        #pragma unroll
        for (int r = 0; r < 16; ++r) {
            int rr = wm + mt * 32 + (r & 3) + 8 * (r >> 2) + 4 * khalf;
            int h = h0 + rr;
            float tv = t1[b * H_ + h];
            float vv = v[h];
            pn0 += vv * tanh_fast(acc[mt][0][r] * 0.015625f + tv);
            pn1 += vv * tanh_fast(acc[mt][1][r] * 0.015625f + tv);
        }
    pn0 += __shfl_xor(pn0, 32);
    pn1 += __shfl_xor(pn1, 32);
    if (lane < 32) {
        atomicAdd(&logits[(size_t)b * S_ + s0 + wn + l32], pn0);
        atomicAdd(&logits[(size_t)b * S_ + s0 + wn + 32 + l32], pn1);
    }
}

// ---------------------------------------------------------------------------
// Fused softmax + context, fp32-exact from original enc.
// grid (8 s-chunks, B). Each block: redundant full softmax of logits[b,:]
// into LDS; then accumulates its 128 s-rows over all 1024 h (h across lanes,
// coalesced float4); atomicAdd into ctx. blockIdx.x==0 writes scores.
// ---------------------------------------------------------------------------
__global__ __launch_bounds__(256) void ctx_kernel(
    const float* __restrict__ enc, const float* __restrict__ logits,
    float* __restrict__ scores, float* __restrict__ ctx)
{
    __shared__ float sc[1024];
    __shared__ float red[8];
    const int b    = blockIdx.y;
    const int s0   = blockIdx.x * 128;
    const int tid  = threadIdx.x;
    const int lane = tid & 63;
    const int w    = tid >> 6;

    float4 lg = *reinterpret_cast<const float4*>(logits + (size_t)b * S_ + tid * 4);
    float mx = fmaxf(fmaxf(lg.x, lg.y), fmaxf(lg.z, lg.w));
    #pragma unroll
    for (int off = 1; off < 64; off <<= 1) mx = fmaxf(mx, __shfl_xor(mx, off));
    if (lane == 0) red[w] = mx;
    __syncthreads();
    mx = fmaxf(fmaxf(red[0], red[1]), fmaxf(red[2], red[3]));
    const float L2E = 1.44269504088896f;
    float e0 = __builtin_amdgcn_exp2f((lg.x - mx) * L2E);
    float e1 = __builtin_amdgcn_exp2f((lg.y - mx) * L2E);
    float e2 = __builtin_amdgcn_exp2f((lg.z - mx) * L2E);
    float e3 = __builtin_amdgcn_exp2f((lg.w - mx) * L2E);
    float s = e0 + e1 + e2 + e3;
    #pragma unroll
    for (int off = 1; off < 64; off <<= 1) s += __shfl_xor(s, off);
    if (lane == 0) red[4 + w] = s;
    __syncthreads();
    float inv = 1.f / (red[4] + red[5] + red[6] + red[7]);
    float4 sv = { e0 * inv, e1 * inv, e2 * inv, e3 * inv };
    *reinterpret_cast<float4*>(&sc[tid * 4]) = sv;
    if (blockIdx.x == 0)
        *reinterpret_cast<float4*>(scores + (size_t)b * S_ + tid * 4) = sv;
    __syncthreads();

    f32x4_t accv = {0.f, 0.f, 0.f, 0.f};
    const float* ebase = enc + ((size_t)b * S_ + s0) * H_ + tid * 4;
    #pragma unroll 4
    for (int si = 0; si < 128; ++si) {
        float wgt = sc[s0 + si];
        float4 ev = *reinterpret_cast<const float4*>(ebase + (size_t)si * H_);
        accv[0] += wgt * ev.x;
        accv[1] += wgt * ev.y;
        accv[2] += wgt * ev.z;
        accv[3] += wgt * ev.w;
    }
    float* cp = ctx + (size_t)b * H_ + tid * 4;
    atomicAdd(cp + 0, accv[0]);
    atomicAdd(cp + 1, accv[1]);
    atomicAdd(cp + 2, accv[2]);
    atomicAdd(cp + 3, accv[3]);
}

// ---------------------------------------------------------------------------
extern "C" void kernel_launch(void* const* d_in, const int* in_sizes, int n_in,
                              void* d_out, int out_size, void* d_ws, size_t ws_size,
                              hipStream_t stream)
{
    (void)in_sizes; (void)n_in; (void)out_size; (void)ws_size;
    const float* hidden = (const float*)d_in[0];
    const float* enc    = (const float*)d_in[1];
    const float* W      = (const float*)d_in[2];
    const float* bias   = (const float*)d_in[3];
    const float* v      = (const float*)d_in[4];

    float* out    = (float*)d_out;
    float* ctx    = out;             // [B,H]
    float* scores = out + B_ * H_;   // [B,S]

    float* logits = (float*)d_ws;                 // B*S f32   (128 KB)
    float* t1     = logits + B_ * S_;             // B*H f32   (128 KB)
    u8*    W2f8   = (u8*)(t1 + B_ * H_);          // 1 MB, k-tiled
    u8*    encF8  = W2f8 + (size_t)H_ * H_;       // 32 MB, k-tiled

    prep_kernel<<<dim3(8192 + 1024 + 256), 256, 0, stream>>>(
        enc, W, hidden, bias, encF8, W2f8, t1, logits, ctx);
    energy_kernel<<<dim3(H_ / 128, S_ / 128, B_), 256, 0, stream>>>(
        W2f8, encF8, t1, v, logits);
    ctx_kernel<<<dim3(S_ / 128, B_), 256, 0, stream>>>(enc, logits, scores, ctx);
}